// Round 11
// baseline (263.048 us; speedup 1.0000x reference)
//
#include <hip/hip_runtime.h>
#include <stdint.h>

typedef __attribute__((ext_vector_type(4))) float  f32x4;
typedef __attribute__((ext_vector_type(8))) __bf16 bf16x8;

constexpr int F_DIM = 128;   // feature dim
constexpr int KC    = 256;   // number of centers
// u = max(sq, 1e-24)^(-1/(M-1)),  M = 1.7  ->  exponent on sq is -1/0.7
constexpr float ALPHA = -1.4285714285714286f;

// ---------------------------------------------------------------------------
// Pre-kernel: centers (fp32, row-major) -> d_ws as {linear bf16 image (64 KiB),
// c2 table (1 KiB)}. Runs once per launch; stays hot in every XCD's L2.
// ---------------------------------------------------------------------------
__global__ __launch_bounds__(64) void fcm_prep(
        const float* __restrict__ centers,
        __bf16* __restrict__ wsB,
        float* __restrict__ wsC2)
{
    const int j    = blockIdx.x;     // center 0..255
    const int lane = threadIdx.x;    // 0..63, handles elements 2*lane, 2*lane+1
    const float2 v = *(const float2*)(centers + j * F_DIM + 2 * lane);
    wsB[j * F_DIM + 2 * lane]     = (__bf16)v.x;
    wsB[j * F_DIM + 2 * lane + 1] = (__bf16)v.y;

    float ss = v.x * v.x + v.y * v.y;
    ss += __shfl_xor(ss, 1);  ss += __shfl_xor(ss, 2);  ss += __shfl_xor(ss, 4);
    ss += __shfl_xor(ss, 8);  ss += __shfl_xor(ss, 16); ss += __shfl_xor(ss, 32);
    if (lane == 0) wsC2[j] = ss;
}

// ---------------------------------------------------------------------------
// Main kernel: fine-grained blocks. One 16-row x-tile per 512-thread block;
// wave w holds centers [w*32, w*32+32) as reg-resident MFMA A-frags (loaded
// from the L2-hot image). No center staging, no DMA drain, straight-line
// code, one tiny barrier for the cross-wave rowsum. ~0.5us block rounds keep
// the CU's HBM demand continuous.
// ---------------------------------------------------------------------------
__global__ __launch_bounds__(512, 4) void fcm_kernel(
        const float* __restrict__ x,
        const __bf16* __restrict__ wsB,
        const float* __restrict__ wsC2,
        float* __restrict__ out)
{
    __shared__ float sPart[16][8];   // [x-row][wave] partial rowsums, 512 B

    const int tid  = threadIdx.x;
    const int lane = tid & 63;
    const int wave = tid >> 6;

    const int lrow = lane & 15;      // x-row / center-row within a 16-tile
    const int kq   = lane >> 4;      // k-quarter 0..3

    const int rbase = blockIdx.x * 16;   // this block's 16 x-rows
    const int cbase = wave * 32;         // this wave's 32 centers

    // ---- center A-frags (8 coalesced dwordx4, L1/L2-hot) + c2 (per-lane) ----
    const __bf16* cb = wsB + (cbase + lrow) * F_DIM + kq * 8;
    bf16x8 fragC[2][4];
    #pragma unroll
    for (int ct = 0; ct < 2; ++ct)
        #pragma unroll
        for (int kb = 0; kb < 4; ++kb)
            fragC[ct][kb] = *(const bf16x8*)(cb + ct * 16 * F_DIM + kb * 32);

    f32x4 c2v[2];
    #pragma unroll
    for (int ct = 0; ct < 2; ++ct)
        c2v[ct] = *(const f32x4*)(wsC2 + cbase + ct * 16 + kq * 4);

    // ---- x B-frags (8 dwordx4 from HBM) + exact fp32 x2 ----
    const float* xrow = x + (long long)(rbase + lrow) * F_DIM + kq * 8;
    bf16x8 fragX[4];
    float x2 = 0.f;
    #pragma unroll
    for (int kb = 0; kb < 4; ++kb) {
        f32x4 a = *(const f32x4*)(xrow + kb * 32);
        f32x4 b = *(const f32x4*)(xrow + kb * 32 + 4);
        x2 += a.x*a.x + a.y*a.y + a.z*a.z + a.w*a.w;
        x2 += b.x*b.x + b.y*b.y + b.z*b.z + b.w*b.w;
        union { __bf16 bh[8]; bf16x8 v; } pk;
        pk.bh[0] = (__bf16)a.x; pk.bh[1] = (__bf16)a.y;
        pk.bh[2] = (__bf16)a.z; pk.bh[3] = (__bf16)a.w;
        pk.bh[4] = (__bf16)b.x; pk.bh[5] = (__bf16)b.y;
        pk.bh[6] = (__bf16)b.z; pk.bh[7] = (__bf16)b.w;
        fragX[kb] = pk.v;
    }
    // lanes {l, l^16, l^32, l^48} hold disjoint k-quarters of row (lane&15)
    x2 += __shfl_xor(x2, 16);
    x2 += __shfl_xor(x2, 32);
    // every lane now holds ||x_row||^2 for its row (lane&15)

    // ---- MFMA: D[center][x-row]; both operands in registers ----
    // D layout: col = lane&15 -> x-row; row = kq*4 + r -> center (cbase+ct*16+..)
    f32x4 acc[2] = { f32x4{0.f,0.f,0.f,0.f}, f32x4{0.f,0.f,0.f,0.f} };
    #pragma unroll
    for (int ct = 0; ct < 2; ++ct)
        #pragma unroll
        for (int kb = 0; kb < 4; ++kb)
            acc[ct] = __builtin_amdgcn_mfma_f32_16x16x32_bf16(fragC[ct][kb], fragX[kb], acc[ct], 0, 0, 0);

    // ---- u = sq^ALPHA; wave-level partial rowsum (32 centers) ----
    float part = 0.f;
    #pragma unroll
    for (int ct = 0; ct < 2; ++ct)
        #pragma unroll
        for (int r = 0; r < 4; ++r) {
            float sq = fmaxf(x2 + c2v[ct][r] - 2.0f * acc[ct][r], 1e-24f);
            float u  = __builtin_amdgcn_exp2f(ALPHA * __builtin_amdgcn_logf(sq));
            acc[ct][r] = u;
            part += u;
        }
    // sum across the 4 kq groups (each holds a disjoint 8-center subset of row)
    part += __shfl_xor(part, 16);
    part += __shfl_xor(part, 32);

    // ---- cross-wave rowsum via 512 B LDS exchange (one barrier) ----
    if (kq == 0) sPart[lrow][wave] = part;
    __syncthreads();
    f32x4 p0 = *(const f32x4*)&sPart[lrow][0];
    f32x4 p1 = *(const f32x4*)&sPart[lrow][4];
    const float tot = (p0.x + p0.y + p0.z + p0.w) + (p1.x + p1.y + p1.z + p1.w);
    const float rinv = __builtin_amdgcn_rcpf(tot);

    // ---- store: wave w covers bytes [w*128, w*128+128) of each 1 KiB row ----
    float* orow = out + (long long)(rbase + lrow) * KC + cbase + kq * 4;
    #pragma unroll
    for (int ct = 0; ct < 2; ++ct) {
        f32x4 v = acc[ct] * rinv;
        *(f32x4*)(orow + ct * 16) = v;
    }
}

extern "C" void kernel_launch(void* const* d_in, const int* in_sizes, int n_in,
                              void* d_out, int out_size, void* d_ws, size_t ws_size,
                              hipStream_t stream) {
    const float* x       = (const float*)d_in[0];
    const float* centers = (const float*)d_in[1];
    float* out           = (float*)d_out;

    __bf16* wsB  = (__bf16*)d_ws;                          // 64 KiB linear bf16
    float*  wsC2 = (float*)((char*)d_ws + KC * F_DIM * 2); // 1 KiB c2 table

    const int N      = in_sizes[0] / F_DIM;   // 262144
    const int blocks = N / 16;                // one 16-row tile per block

    fcm_prep<<<KC, 64, 0, stream>>>(centers, wsB, wsC2);
    fcm_kernel<<<blocks, 512, 0, stream>>>(x, wsB, wsC2, out);
}